// Round 6
// baseline (526.857 us; speedup 1.0000x reference)
//
#include <hip/hip_runtime.h>
#include <hip/hip_bf16.h>
#include <math.h>

typedef __attribute__((ext_vector_type(8))) short frag8;   // 8 bf16 (4 VGPRs)
typedef __attribute__((ext_vector_type(4))) float f32x4;

// ---------------- device helpers ----------------
__device__ __forceinline__ float gelu_exact(float x) {
    return 0.5f * x * (1.0f + erff(x * 0.70710678118654752f));
}
__device__ __forceinline__ float softplus_f(float x) {
    return (x > 20.0f) ? x : log1pf(expf(x));
}
__device__ __forceinline__ float sigmoid_f(float x) {
    return 1.0f / (1.0f + __expf(-x));
}
__device__ __forceinline__ unsigned short bf16bits(float x) {
    __hip_bfloat16 h = __float2bfloat16(x);
    return *(unsigned short*)&h;
}
// sum over the 16 lanes of each DPP row-of-16 — VALU-pipe only
__device__ __forceinline__ float row_sum16(float x) {
    int t;
    t = __builtin_amdgcn_update_dpp(0, __builtin_bit_cast(int, x), 0x128, 0xf, 0xf, true); // row_ror:8
    x += __builtin_bit_cast(float, t);
    t = __builtin_amdgcn_update_dpp(0, __builtin_bit_cast(int, x), 0x124, 0xf, 0xf, true); // row_ror:4
    x += __builtin_bit_cast(float, t);
    t = __builtin_amdgcn_update_dpp(0, __builtin_bit_cast(int, x), 0x122, 0xf, 0xf, true); // row_ror:2
    x += __builtin_bit_cast(float, t);
    t = __builtin_amdgcn_update_dpp(0, __builtin_bit_cast(int, x), 0x121, 0xf, 0xf, true); // row_ror:1
    x += __builtin_bit_cast(float, t);
    return x;
}

// ---------------- fused fp32 -> bf16 conversion ----------------
struct CvtArgs {
    const float* src[7];
    unsigned short* dst[7];
    int n4[7];
};
__global__ __launch_bounds__(256)
void cvt_all(CvtArgs a, int total4)
{
    int i = blockIdx.x * 256 + threadIdx.x;
    if (i >= total4) return;
    int seg = 0;
    while (i >= a.n4[seg]) { i -= a.n4[seg]; seg++; }
    float4 v = reinterpret_cast<const float4*>(a.src[seg])[i];
    ushort4 o;
    o.x = bf16bits(v.x); o.y = bf16bits(v.y); o.z = bf16bits(v.z); o.w = bf16bits(v.w);
    reinterpret_cast<ushort4*>(a.dst[seg])[i] = o;
}

// ---------------- generic MFMA bf16 GEMM (64x64 tile) ----------------
__global__ __launch_bounds__(256)
void gemm_mfma(const unsigned short* __restrict__ A,
               const unsigned short* __restrict__ W,
               const float* __restrict__ bias,
               float* __restrict__ C,
               int N, int K)
{
    __shared__ __align__(16) unsigned short As[64][40];
    __shared__ __align__(16) unsigned short Bs[64][40];

    const int tid = threadIdx.x;
    const int wid = tid >> 6, lane = tid & 63;
    const int wm = (wid >> 1) * 32, wn = (wid & 1) * 32;
    const int m0 = blockIdx.y * 64, n0 = blockIdx.x * 64;
    const int lrow = lane & 15, quad = lane >> 4;

    const int sm = tid >> 2;
    const int sk = (tid & 3) * 8;

    f32x4 acc[2][2] = {};

    for (int k0 = 0; k0 < K; k0 += 32) {
        float4 av = *reinterpret_cast<const float4*>(A + (size_t)(m0 + sm) * K + k0 + sk);
        *reinterpret_cast<float4*>(&As[sm][sk]) = av;
        float4 bv = {0.f, 0.f, 0.f, 0.f};
        int n = n0 + sm;
        if (n < N) bv = *reinterpret_cast<const float4*>(W + (size_t)n * K + k0 + sk);
        *reinterpret_cast<float4*>(&Bs[sm][sk]) = bv;
        __syncthreads();

        frag8 a0 = *reinterpret_cast<const frag8*>(&As[wm + lrow][quad * 8]);
        frag8 a1 = *reinterpret_cast<const frag8*>(&As[wm + 16 + lrow][quad * 8]);
        frag8 b0 = *reinterpret_cast<const frag8*>(&Bs[wn + lrow][quad * 8]);
        frag8 b1 = *reinterpret_cast<const frag8*>(&Bs[wn + 16 + lrow][quad * 8]);

        acc[0][0] = __builtin_amdgcn_mfma_f32_16x16x32_bf16(a0, b0, acc[0][0], 0, 0, 0);
        acc[0][1] = __builtin_amdgcn_mfma_f32_16x16x32_bf16(a0, b1, acc[0][1], 0, 0, 0);
        acc[1][0] = __builtin_amdgcn_mfma_f32_16x16x32_bf16(a1, b0, acc[1][0], 0, 0, 0);
        acc[1][1] = __builtin_amdgcn_mfma_f32_16x16x32_bf16(a1, b1, acc[1][1], 0, 0, 0);
        __syncthreads();
    }

    #pragma unroll
    for (int mi = 0; mi < 2; mi++) {
        #pragma unroll
        for (int nj = 0; nj < 2; nj++) {
            int col = n0 + wn + nj * 16 + lrow;
            if (col >= N) continue;
            #pragma unroll
            for (int r = 0; r < 4; r++) {
                int row = m0 + wm + mi * 16 + quad * 4 + r;
                float v = acc[mi][nj][r];
                if (bias) v += bias[col];
                C[(size_t)row * N + col] = v;
            }
        }
    }
}

// ---------------- MFMA GEMM, A from ucT [B=4][K=512][T=1024] fp32 ----------------
// Logical A[m][k] with m = b*1024+t lives at ucT[(b*512+k)*1024 + t].
// W: N x K bf16 ; C: M x N fp32. Single n-tile (N<=64). 64-row m-tiles never
// straddle a batch boundary (1024 % 64 == 0).
__global__ __launch_bounds__(256)
void gemm_at(const float* __restrict__ AT,
             const unsigned short* __restrict__ W,
             float* __restrict__ C,
             int N, int K)
{
    __shared__ __align__(16) unsigned short As[64][40];
    __shared__ __align__(16) unsigned short Bs[64][40];

    const int tid = threadIdx.x;
    const int wid = tid >> 6, lane = tid & 63;
    const int wm = (wid >> 1) * 32, wn = (wid & 1) * 32;
    const int m0 = blockIdx.y * 64;
    const int bb = m0 >> 10;          // batch of this m-tile
    const int tb = m0 & 1023;         // t-base of this m-tile
    const int lrow = lane & 15, quad = lane >> 4;

    const int sm = tid >> 2;
    const int sk = (tid & 3) * 8;

    f32x4 acc[2][2] = {};

    for (int k0 = 0; k0 < K; k0 += 32) {
        // stage A from ucT[(bb*512 + k)*1024 + tb + mm], converting fp32->bf16
        #pragma unroll
        for (int p = 0; p < 2; p++) {
            int kk = (tid >> 4) + p * 16;          // 0..31
            int mq = tid & 15;                     // float4 index along m
            float4 v = *reinterpret_cast<const float4*>(AT + ((size_t)(bb * 512 + k0 + kk)) * 1024 + tb + mq * 4);
            As[mq * 4 + 0][kk] = bf16bits(v.x);
            As[mq * 4 + 1][kk] = bf16bits(v.y);
            As[mq * 4 + 2][kk] = bf16bits(v.z);
            As[mq * 4 + 3][kk] = bf16bits(v.w);
        }
        float4 bv = {0.f, 0.f, 0.f, 0.f};
        if (sm < N) bv = *reinterpret_cast<const float4*>(W + (size_t)sm * K + k0 + sk);
        *reinterpret_cast<float4*>(&Bs[sm][sk]) = bv;
        __syncthreads();

        frag8 a0 = *reinterpret_cast<const frag8*>(&As[wm + lrow][quad * 8]);
        frag8 a1 = *reinterpret_cast<const frag8*>(&As[wm + 16 + lrow][quad * 8]);
        frag8 b0 = *reinterpret_cast<const frag8*>(&Bs[wn + lrow][quad * 8]);
        frag8 b1 = *reinterpret_cast<const frag8*>(&Bs[wn + 16 + lrow][quad * 8]);

        acc[0][0] = __builtin_amdgcn_mfma_f32_16x16x32_bf16(a0, b0, acc[0][0], 0, 0, 0);
        acc[0][1] = __builtin_amdgcn_mfma_f32_16x16x32_bf16(a0, b1, acc[0][1], 0, 0, 0);
        acc[1][0] = __builtin_amdgcn_mfma_f32_16x16x32_bf16(a1, b0, acc[1][0], 0, 0, 0);
        acc[1][1] = __builtin_amdgcn_mfma_f32_16x16x32_bf16(a1, b1, acc[1][1], 0, 0, 0);
        __syncthreads();
    }

    #pragma unroll
    for (int mi = 0; mi < 2; mi++) {
        #pragma unroll
        for (int nj = 0; nj < 2; nj++) {
            int col = wn + nj * 16 + lrow;
            if (col >= N) continue;
            #pragma unroll
            for (int r = 0; r < 4; r++) {
                int row = m0 + wm + mi * 16 + quad * 4 + r;
                C[(size_t)row * N + col] = acc[mi][nj][r];
            }
        }
    }
}

// ---------------- full-row GEMM (N=256) with fused LN / GELU / residual / L2 ----
__global__ __launch_bounds__(256)
void rowgemm(const unsigned short* __restrict__ A,
             const unsigned short* __restrict__ W,
             const float* __restrict__ bias,
             const float* res,
             const float* g1, const float* b1, int gelu1,
             const float* g2, const float* b2,
             float* outF, unsigned short* outB, float* l2out, int K)
{
    __shared__ __align__(16) unsigned short As[16][40];
    __shared__ __align__(16) unsigned short Bs[256][40];
    __shared__ float red[4][16][2];
    __shared__ float sq[16];

    const int tid = threadIdx.x;
    const int w = tid >> 6, lane = tid & 63;
    const int lrow = lane & 15, quad = lane >> 4;
    const int m0 = blockIdx.x * 16;

    f32x4 acc[4] = {};

    for (int k0 = 0; k0 < K; k0 += 32) {
        if (tid < 64) {
            float4 av = *reinterpret_cast<const float4*>(A + (size_t)(m0 + (tid >> 2)) * K + k0 + (tid & 3) * 8);
            *reinterpret_cast<float4*>(&As[tid >> 2][(tid & 3) * 8]) = av;
        }
        #pragma unroll
        for (int i = 0; i < 4; i++) {
            int n = (tid >> 2) + i * 64;
            float4 bv = *reinterpret_cast<const float4*>(W + (size_t)n * K + k0 + (tid & 3) * 8);
            *reinterpret_cast<float4*>(&Bs[n][(tid & 3) * 8]) = bv;
        }
        __syncthreads();
        frag8 a = *reinterpret_cast<const frag8*>(&As[lrow][quad * 8]);
        #pragma unroll
        for (int nj = 0; nj < 4; nj++) {
            frag8 b = *reinterpret_cast<const frag8*>(&Bs[w * 64 + nj * 16 + lrow][quad * 8]);
            acc[nj] = __builtin_amdgcn_mfma_f32_16x16x32_bf16(a, b, acc[nj], 0, 0, 0);
        }
        __syncthreads();
    }

    float v[4][4];
    #pragma unroll
    for (int nj = 0; nj < 4; nj++) {
        int col = w * 64 + nj * 16 + lrow;
        #pragma unroll
        for (int r = 0; r < 4; r++) {
            int row = m0 + quad * 4 + r;
            float t = acc[nj][r];
            if (bias) t += bias[col];
            if (res) t += res[(size_t)row * 256 + col];
            v[nj][r] = t;
        }
    }

    if (g1) {
        #pragma unroll
        for (int r = 0; r < 4; r++) {
            float s1 = v[0][r] + v[1][r] + v[2][r] + v[3][r];
            float s2 = v[0][r]*v[0][r] + v[1][r]*v[1][r] + v[2][r]*v[2][r] + v[3][r]*v[3][r];
            s1 = row_sum16(s1); s2 = row_sum16(s2);
            if (lrow == 0) { red[w][quad * 4 + r][0] = s1; red[w][quad * 4 + r][1] = s2; }
        }
        __syncthreads();
        #pragma unroll
        for (int r = 0; r < 4; r++) {
            int rr = quad * 4 + r;
            float t1 = red[0][rr][0] + red[1][rr][0] + red[2][rr][0] + red[3][rr][0];
            float t2 = red[0][rr][1] + red[1][rr][1] + red[2][rr][1] + red[3][rr][1];
            float mu = t1 * (1.0f / 256.0f);
            float var = t2 * (1.0f / 256.0f) - mu * mu;
            float rstd = rsqrtf(var + 1e-5f);
            #pragma unroll
            for (int nj = 0; nj < 4; nj++) {
                int col = w * 64 + nj * 16 + lrow;
                float t = (v[nj][r] - mu) * rstd * g1[col] + b1[col];
                if (gelu1) t = gelu_exact(t);
                v[nj][r] = t;
            }
        }
        __syncthreads();
    } else if (gelu1) {
        #pragma unroll
        for (int nj = 0; nj < 4; nj++)
            #pragma unroll
            for (int r = 0; r < 4; r++)
                v[nj][r] = gelu_exact(v[nj][r]);
    }

    if (outF) {
        #pragma unroll
        for (int nj = 0; nj < 4; nj++) {
            int col = w * 64 + nj * 16 + lrow;
            #pragma unroll
            for (int r = 0; r < 4; r++)
                outF[(size_t)(m0 + quad * 4 + r) * 256 + col] = v[nj][r];
        }
    }

    if (l2out) {
        #pragma unroll
        for (int r = 0; r < 4; r++) {
            float s2 = v[0][r]*v[0][r] + v[1][r]*v[1][r] + v[2][r]*v[2][r] + v[3][r]*v[3][r];
            s2 = row_sum16(s2);
            if (lrow == 0) red[w][quad * 4 + r][0] = s2;
        }
        __syncthreads();
        if (tid < 16) {
            float t = red[0][tid][0] + red[1][tid][0] + red[2][tid][0] + red[3][tid][0];
            sq[tid] = sqrtf(t);
        }
        __syncthreads();
        if (tid == 0) {
            float a = 0.f;
            #pragma unroll
            for (int i = 0; i < 16; i++) a += sq[i];
            atomicAdd(l2out, a * (0.01f / 4096.0f));
        }
    }

    if (g2) {
        __syncthreads();
        #pragma unroll
        for (int r = 0; r < 4; r++) {
            float s1 = v[0][r] + v[1][r] + v[2][r] + v[3][r];
            float s2 = v[0][r]*v[0][r] + v[1][r]*v[1][r] + v[2][r]*v[2][r] + v[3][r]*v[3][r];
            s1 = row_sum16(s1); s2 = row_sum16(s2);
            if (lrow == 0) { red[w][quad * 4 + r][0] = s1; red[w][quad * 4 + r][1] = s2; }
        }
        __syncthreads();
        #pragma unroll
        for (int r = 0; r < 4; r++) {
            int rr = quad * 4 + r;
            float t1 = red[0][rr][0] + red[1][rr][0] + red[2][rr][0] + red[3][rr][0];
            float t2 = red[0][rr][1] + red[1][rr][1] + red[2][rr][1] + red[3][rr][1];
            float mu = t1 * (1.0f / 256.0f);
            float var = t2 * (1.0f / 256.0f) - mu * mu;
            float rstd = rsqrtf(var + 1e-5f);
            #pragma unroll
            for (int nj = 0; nj < 4; nj++) {
                int col = w * 64 + nj * 16 + lrow;
                outB[(size_t)(m0 + rr) * 256 + col] = bf16bits((v[nj][r] - mu) * rstd * g2[col] + b2[col]);
            }
        }
    } else if (outB) {
        #pragma unroll
        for (int nj = 0; nj < 4; nj++) {
            int col = w * 64 + nj * 16 + lrow;
            #pragma unroll
            for (int r = 0; r < 4; r++)
                outB[(size_t)(m0 + quad * 4 + r) * 256 + col] = bf16bits(v[nj][r]);
        }
    }
}

// ---------------- conv + SiLU, writing u^T [b][d][t] fp32 ----------------
// grid 512: b(4) x dtile(8,64d) x ttile(16,64t); 256 threads
__global__ __launch_bounds__(256)
void conv_silu_T(const float* __restrict__ xz, const float* __restrict__ cw,
                 const float* __restrict__ cb, float* __restrict__ ucT)
{
    __shared__ float xs[67][65];
    const int bx = blockIdx.x;
    const int b = bx >> 7;
    const int dt_ = (bx & 127) >> 4;
    const int tt = bx & 15;
    const int tid = threadIdx.x;
    const int d0 = dt_ * 64, t0 = tt * 64;

    for (int i = tid; i < 67 * 64; i += 256) {
        int rr = i >> 6, dd = i & 63;
        int tg = t0 - 3 + rr;
        xs[rr][dd] = (tg >= 0) ? xz[((size_t)(b * 1024 + tg)) * 1024 + d0 + dd] : 0.0f;
    }
    __syncthreads();

    const int tl = tid & 63, dgrp = tid >> 6;
    #pragma unroll 4
    for (int dp = 0; dp < 16; dp++) {
        int dd = dp * 4 + dgrp;
        int d = d0 + dd;
        float c0 = cw[d * 4 + 0], c1 = cw[d * 4 + 1], c2 = cw[d * 4 + 2], c3 = cw[d * 4 + 3];
        float acc = cb[d] + xs[tl][dd] * c0 + xs[tl + 1][dd] * c1 + xs[tl + 2][dd] * c2 + xs[tl + 3][dd] * c3;
        ucT[((size_t)(b * 512 + d)) * 1024 + t0 + tl] = acc * sigmoid_f(acc);
    }
}

// ---------------- dt projection + softplus, writing delta^T [b][d][t] ----------
// grid 64: b(4) x ttile(16,64t); 256 threads (4 waves, wave w -> d in [w*128,w*128+128))
__global__ __launch_bounds__(256)
void dt_softplus_T(const float* __restrict__ xdbc, const float* __restrict__ dtw,
                   const float* __restrict__ dtb, float* __restrict__ dltT)
{
    __shared__ float xd[64][17];
    const int b = blockIdx.x >> 4;
    const int tt = blockIdx.x & 15;
    const int tid = threadIdx.x;
    const int t0 = tt * 64;

    for (int i = tid; i < 64 * 16; i += 256) {
        int t = i >> 4, k = i & 15;
        xd[t][k] = xdbc[((size_t)(b * 1024 + t0 + t)) * 48 + k];
    }
    __syncthreads();

    const int tl = tid & 63, w = tid >> 6;
    for (int di = 0; di < 128; di++) {
        int d = w * 128 + di;
        float acc = dtb[d];
        #pragma unroll
        for (int k = 0; k < 16; k++) acc += xd[tl][k] * dtw[d * 16 + k];
        dltT[((size_t)(b * 512 + d)) * 1024 + t0 + tl] = softplus_f(acc);
    }
}

// ---------------- B/C transpose: xdbc[.,16:48] -> BT/CT [b][s][t] ----------------
// grid 16: b(4) x ttile(4,256t); 256 threads
__global__ __launch_bounds__(256)
void bc_trans(const float* __restrict__ xdbc, float* __restrict__ BT, float* __restrict__ CT)
{
    __shared__ float sx[256][33];
    const int b = blockIdx.x >> 2;
    const int tt = blockIdx.x & 3;
    const int tid = threadIdx.x;
    const int t0 = tt * 256;

    for (int i = tid; i < 256 * 32; i += 256) {
        int t = i >> 5, c = i & 31;
        sx[t][c] = xdbc[((size_t)(b * 1024 + t0 + t)) * 48 + 16 + c];
    }
    __syncthreads();
    for (int i = tid; i < 32 * 256; i += 256) {
        int c = i >> 8, t = i & 255;
        float v = sx[t][c];
        if (c < 16) BT[((size_t)(b * 16 + c)) * 1024 + t0 + t] = v;
        else        CT[((size_t)(b * 16 + c - 16)) * 1024 + t0 + t] = v;
    }
}

// ---------------- chunked selective scan, float4 transposed loads ----------------
__global__ __launch_bounds__(1024)
void scan_chunked(const float* __restrict__ dltT, const float* __restrict__ ucT,
                  const float* __restrict__ BT, const float* __restrict__ CT,
                  const float* __restrict__ xz,
                  const float* __restrict__ A_log, const float* __restrict__ Dp,
                  unsigned short* __restrict__ y)
{
    __shared__ float aprod_s[16][64];
    __shared__ float sfin_s[16][64];
    __shared__ float sin_s[16][64];
    __shared__ float ylocal[16][64][4];
    __shared__ float ycorr[16][64][4];

    const int j = blockIdx.x;
    const int bid = (j & 7) * 64 + (j >> 3);     // XCD swizzle
    const int b = bid >> 7;
    const int d0 = (bid & 127) * 4;
    const int w = threadIdx.x >> 6;
    const int lane = threadIdx.x & 63;
    const int dsub = lane >> 4, s = lane & 15;
    const int d = d0 + dsub;

    const float Acoef = -__expf(A_log[d * 16 + s]);

    const float4* dp = reinterpret_cast<const float4*>(dltT + ((size_t)(b * 512 + d)) * 1024 + w * 64);
    const float4* up = reinterpret_cast<const float4*>(ucT  + ((size_t)(b * 512 + d)) * 1024 + w * 64);
    const float4* Bp = reinterpret_cast<const float4*>(BT + ((size_t)(b * 16 + s)) * 1024 + w * 64);
    const float4* Cp = reinterpret_cast<const float4*>(CT + ((size_t)(b * 16 + s)) * 1024 + w * 64);

    // ---- Phase A: local scan with cumprod ----
    float st = 0.0f, ap = 1.0f;
    #pragma unroll 2
    for (int q = 0; q < 16; q++) {
        float4 dt4 = dp[q], ut4 = up[q], B4 = Bp[q], C4 = Cp[q];
        const float* dtp = (const float*)&dt4;
        const float* utp = (const float*)&ut4;
        const float* Btp = (const float*)&B4;
        const float* Ctp = (const float*)&C4;
        #pragma unroll
        for (int jj = 0; jj < 4; jj++) {
            float dA = __expf(dtp[jj] * Acoef);
            st = st * dA + dtp[jj] * utp[jj] * Btp[jj];
            ap *= dA;
            float part = row_sum16(st * Ctp[jj]);
            if (s == 0) ylocal[w][q * 4 + jj][dsub] = part;
        }
    }
    aprod_s[w][lane] = ap;
    sfin_s[w][lane] = st;
    __syncthreads();

    // ---- Phase B: chunk-summary scan ----
    if (w == 0) {
        float pre = 0.0f;
        #pragma unroll
        for (int c = 0; c < 16; c++) {
            sin_s[c][lane] = pre;
            pre = sfin_s[c][lane] + aprod_s[c][lane] * pre;
        }
    }
    __syncthreads();

    // ---- Phase C: correction ----
    float g = sin_s[w][lane];
    #pragma unroll 2
    for (int q = 0; q < 16; q++) {
        float4 dt4 = dp[q], C4 = Cp[q];
        const float* dtp = (const float*)&dt4;
        const float* Ctp = (const float*)&C4;
        #pragma unroll
        for (int jj = 0; jj < 4; jj++) {
            g *= __expf(dtp[jj] * Acoef);
            float part = row_sum16(g * Ctp[jj]);
            if (s == 0) ycorr[w][q * 4 + jj][dsub] = part;
        }
    }

    // ---- vectorized epilogue: lane = t within chunk ----
    const int t = w * 64 + lane;
    const size_t row = (size_t)b * 1024 + t;
    #pragma unroll
    for (int dd = 0; dd < 4; dd++) {
        float ut = ucT[((size_t)(b * 512 + d0 + dd)) * 1024 + t];
        float zt = xz[row * 1024 + 512 + d0 + dd];
        float yv = ylocal[w][lane][dd] + ycorr[w][lane][dd] + ut * Dp[d0 + dd];
        y[row * 512 + d0 + dd] = bf16bits(yv * (zt * sigmoid_f(zt)));
    }
}

// ---------------- misc ----------------
__global__ void zero_one(float* p) { if (threadIdx.x == 0 && blockIdx.x == 0) *p = 0.0f; }

// ---------------- launcher ----------------
extern "C" void kernel_launch(void* const* d_in, const int* in_sizes, int n_in,
                              void* d_out, int out_size, void* d_ws, size_t ws_size,
                              hipStream_t stream)
{
    const float* x      = (const float*)d_in[0];
    const float* in_b   = (const float*)d_in[2];
    const float* ln_g   = (const float*)d_in[3];
    const float* ln_b   = (const float*)d_in[4];
    const float* blk_ng  = (const float*)d_in[5];
    const float* blk_nb  = (const float*)d_in[6];
    const float* blk_cw  = (const float*)d_in[8];
    const float* blk_cb  = (const float*)d_in[9];
    const float* blk_dtw = (const float*)d_in[11];
    const float* blk_dtb = (const float*)d_in[12];
    const float* blk_Alog= (const float*)d_in[13];
    const float* blk_D   = (const float*)d_in[14];
    const float* op_b   = (const float*)d_in[17];
    const float* cls_b  = (const float*)d_in[19];
    float* out = (float*)d_out;

    const int BL = 4096;
    float* ws = (float*)d_ws;
    float* h0   = ws;                         // 1,048,576
    float* xz   = h0 + 1048576;               // 4,194,304
    float* ucT  = xz + 4194304;               // 2,097,152  [b][d][t]
    float* xdbc = ucT + 2097152;              //   196,608
    float* dltT = xdbc + 196608;              // 2,097,152  [b][d][t]
    float* BT   = dltT + 2097152;             //    65,536  [b][s][t]
    float* CT   = BT + 65536;                 //    65,536  [b][s][t]
    unsigned short* wb  = (unsigned short*)(CT + 65536);
    unsigned short* hnb = wb + 1130496;       // 1,048,576
    unsigned short* ybb = hnb + 1048576;      // 2,097,152
    unsigned short* xb  = (unsigned short*)dltT;  // x bf16 (dead before dltT written)
    unsigned short* h0b = hnb;
    unsigned short* h2b = ybb;
    unsigned short* in_wb  = wb;
    unsigned short* ipw_b  = wb + 196608;
    unsigned short* xpw_b  = wb + 720896;
    unsigned short* opw_b  = wb + 770048;
    unsigned short* op_wb  = wb + 1032192;
    unsigned short* cls_wb = wb + 1097728;

    CvtArgs ca;
    ca.src[0] = x;                  ca.dst[0] = xb;     ca.n4[0] = 3145728 / 4;
    ca.src[1] = (const float*)d_in[1];  ca.dst[1] = in_wb;  ca.n4[1] = 196608 / 4;
    ca.src[2] = (const float*)d_in[7];  ca.dst[2] = ipw_b;  ca.n4[2] = 524288 / 4;
    ca.src[3] = (const float*)d_in[10]; ca.dst[3] = xpw_b;  ca.n4[3] = 49152 / 4;
    ca.src[4] = (const float*)d_in[15]; ca.dst[4] = opw_b;  ca.n4[4] = 262144 / 4;
    ca.src[5] = (const float*)d_in[16]; ca.dst[5] = op_wb;  ca.n4[5] = 65536 / 4;
    ca.src[6] = (const float*)d_in[18]; ca.dst[6] = cls_wb; ca.n4[6] = 32768 / 4;
    int total4 = (3145728 + 1130496) / 4;
    cvt_all<<<(total4 + 255) / 256, 256, 0, stream>>>(ca, total4);
    zero_one<<<1, 1, 0, stream>>>(out + (size_t)BL * 128);

    // in_proj + bias + LN + GELU -> h0 (fp32), + LN(layer0) -> hnb (bf16)
    rowgemm<<<256, 256, 0, stream>>>(xb, in_wb, in_b, nullptr,
                                     ln_g, ln_b, 1,
                                     blk_ng, blk_nb,
                                     h0, hnb, nullptr, 768);

    for (int l = 0; l < 2; l++) {
        const float* cw   = blk_cw  + (size_t)l * 512 * 4;
        const float* cb   = blk_cb  + l * 512;
        const float* dtw  = blk_dtw + (size_t)l * 512 * 16;
        const float* dtb  = blk_dtb + l * 512;
        const float* Alog = blk_Alog+ (size_t)l * 512 * 16;
        const float* Dl   = blk_D   + l * 512;
        const unsigned short* ipwl = ipw_b + (size_t)l * 262144;
        const unsigned short* xpwl = xpw_b + (size_t)l * 24576;
        const unsigned short* opwl = opw_b + (size_t)l * 131072;

        // xz = hnb @ ipw.T   (N=1024, K=256)
        gemm_mfma<<<dim3(16, 64), 256, 0, stream>>>(hnb, ipwl, nullptr, xz, 1024, 256);
        // ucT = silu(conv(u) + cb), transposed [b][d][t]
        conv_silu_T<<<512, 256, 0, stream>>>(xz, cw, cb, ucT);
        // xdbc = u @ xpw.T  (N=48, K=512), A read from ucT [b][k][t]
        gemm_at<<<dim3(1, 64), 256, 0, stream>>>(ucT, xpwl, xdbc, 48, 512);
        // BT/CT transposes + dltT (softplus(dt@dtw.T+dtb), transposed)
        bc_trans<<<16, 256, 0, stream>>>(xdbc, BT, CT);
        dt_softplus_T<<<64, 256, 0, stream>>>(xdbc, dtw, dtb, dltT);
        // scan -> ybb
        scan_chunked<<<512, 1024, 0, stream>>>(dltT, ucT, BT, CT, xz, Alog, Dl, ybb);
        // h0 += ybb @ opw.T; layer0: +LN(layer1)->hnb; layer1: ->h0b bf16 only
        if (l == 0)
            rowgemm<<<256, 256, 0, stream>>>(ybb, opwl, nullptr, h0,
                                             nullptr, nullptr, 0,
                                             blk_ng + 256, blk_nb + 256,
                                             h0, hnb, nullptr, 512);
        else
            rowgemm<<<256, 256, 0, stream>>>(ybb, opwl, nullptr, h0,
                                             nullptr, nullptr, 0,
                                             nullptr, nullptr,
                                             nullptr, h0b, nullptr, 512);
    }

    // h2 = gelu(h0b @ op_w.T + op_b) -> h2b (bf16) + fused L2 scalar
    rowgemm<<<256, 256, 0, stream>>>(h0b, op_wb, op_b, nullptr,
                                     nullptr, nullptr, 1,
                                     nullptr, nullptr,
                                     nullptr, h2b, out + (size_t)BL * 128, 256);
    // logits = h2b @ cls_w.T + cls_b -> d_out (N=128, K=256)
    gemm_mfma<<<dim3(2, 64), 256, 0, stream>>>(h2b, cls_wb, cls_b, out, 128, 256);
}

// Round 7
// 410.711 us; speedup vs baseline: 1.2828x; 1.2828x over previous
//
#include <hip/hip_runtime.h>
#include <hip/hip_bf16.h>
#include <math.h>

typedef __attribute__((ext_vector_type(8))) short frag8;   // 8 bf16 (4 VGPRs)
typedef __attribute__((ext_vector_type(4))) float f32x4;

// ---------------- device helpers ----------------
__device__ __forceinline__ float gelu_exact(float x) {
    return 0.5f * x * (1.0f + erff(x * 0.70710678118654752f));
}
__device__ __forceinline__ float softplus_f(float x) {
    return (x > 20.0f) ? x : log1pf(expf(x));
}
__device__ __forceinline__ float sigmoid_f(float x) {
    return 1.0f / (1.0f + __expf(-x));
}
__device__ __forceinline__ unsigned short bf16bits(float x) {
    __hip_bfloat16 h = __float2bfloat16(x);
    return *(unsigned short*)&h;
}
// sum over the 16 lanes of each DPP row-of-16 — VALU-pipe only
__device__ __forceinline__ float row_sum16(float x) {
    int t;
    t = __builtin_amdgcn_update_dpp(0, __builtin_bit_cast(int, x), 0x128, 0xf, 0xf, true); // row_ror:8
    x += __builtin_bit_cast(float, t);
    t = __builtin_amdgcn_update_dpp(0, __builtin_bit_cast(int, x), 0x124, 0xf, 0xf, true); // row_ror:4
    x += __builtin_bit_cast(float, t);
    t = __builtin_amdgcn_update_dpp(0, __builtin_bit_cast(int, x), 0x122, 0xf, 0xf, true); // row_ror:2
    x += __builtin_bit_cast(float, t);
    t = __builtin_amdgcn_update_dpp(0, __builtin_bit_cast(int, x), 0x121, 0xf, 0xf, true); // row_ror:1
    x += __builtin_bit_cast(float, t);
    return x;
}

// ---------------- fused fp32 -> bf16 conversion ----------------
struct CvtArgs {
    const float* src[7];
    unsigned short* dst[7];
    int n4[7];
};
__global__ __launch_bounds__(256)
void cvt_all(CvtArgs a, int total4)
{
    int i = blockIdx.x * 256 + threadIdx.x;
    if (i >= total4) return;
    int seg = 0;
    while (i >= a.n4[seg]) { i -= a.n4[seg]; seg++; }
    float4 v = reinterpret_cast<const float4*>(a.src[seg])[i];
    ushort4 o;
    o.x = bf16bits(v.x); o.y = bf16bits(v.y); o.z = bf16bits(v.z); o.w = bf16bits(v.w);
    reinterpret_cast<ushort4*>(a.dst[seg])[i] = o;
}

// ---------------- generic MFMA bf16 GEMM (64x64 tile) ----------------
__global__ __launch_bounds__(256)
void gemm_mfma(const unsigned short* __restrict__ A,
               const unsigned short* __restrict__ W,
               const float* __restrict__ bias,
               float* __restrict__ C,
               int N, int K)
{
    __shared__ __align__(16) unsigned short As[64][40];
    __shared__ __align__(16) unsigned short Bs[64][40];

    const int tid = threadIdx.x;
    const int wid = tid >> 6, lane = tid & 63;
    const int wm = (wid >> 1) * 32, wn = (wid & 1) * 32;
    const int m0 = blockIdx.y * 64, n0 = blockIdx.x * 64;
    const int lrow = lane & 15, quad = lane >> 4;

    const int sm = tid >> 2;
    const int sk = (tid & 3) * 8;

    f32x4 acc[2][2] = {};

    for (int k0 = 0; k0 < K; k0 += 32) {
        float4 av = *reinterpret_cast<const float4*>(A + (size_t)(m0 + sm) * K + k0 + sk);
        *reinterpret_cast<float4*>(&As[sm][sk]) = av;
        float4 bv = {0.f, 0.f, 0.f, 0.f};
        int n = n0 + sm;
        if (n < N) bv = *reinterpret_cast<const float4*>(W + (size_t)n * K + k0 + sk);
        *reinterpret_cast<float4*>(&Bs[sm][sk]) = bv;
        __syncthreads();

        frag8 a0 = *reinterpret_cast<const frag8*>(&As[wm + lrow][quad * 8]);
        frag8 a1 = *reinterpret_cast<const frag8*>(&As[wm + 16 + lrow][quad * 8]);
        frag8 b0 = *reinterpret_cast<const frag8*>(&Bs[wn + lrow][quad * 8]);
        frag8 b1 = *reinterpret_cast<const frag8*>(&Bs[wn + 16 + lrow][quad * 8]);

        acc[0][0] = __builtin_amdgcn_mfma_f32_16x16x32_bf16(a0, b0, acc[0][0], 0, 0, 0);
        acc[0][1] = __builtin_amdgcn_mfma_f32_16x16x32_bf16(a0, b1, acc[0][1], 0, 0, 0);
        acc[1][0] = __builtin_amdgcn_mfma_f32_16x16x32_bf16(a1, b0, acc[1][0], 0, 0, 0);
        acc[1][1] = __builtin_amdgcn_mfma_f32_16x16x32_bf16(a1, b1, acc[1][1], 0, 0, 0);
        __syncthreads();
    }

    #pragma unroll
    for (int mi = 0; mi < 2; mi++) {
        #pragma unroll
        for (int nj = 0; nj < 2; nj++) {
            int col = n0 + wn + nj * 16 + lrow;
            if (col >= N) continue;
            #pragma unroll
            for (int r = 0; r < 4; r++) {
                int row = m0 + wm + mi * 16 + quad * 4 + r;
                float v = acc[mi][nj][r];
                if (bias) v += bias[col];
                C[(size_t)row * N + col] = v;
            }
        }
    }
}

// ---------------- MFMA GEMM, A from ucT [B=4][K=512][T=1024] fp32 ----------------
__global__ __launch_bounds__(256)
void gemm_at(const float* __restrict__ AT,
             const unsigned short* __restrict__ W,
             float* __restrict__ C,
             int N, int K)
{
    __shared__ __align__(16) unsigned short As[64][40];
    __shared__ __align__(16) unsigned short Bs[64][40];

    const int tid = threadIdx.x;
    const int wid = tid >> 6, lane = tid & 63;
    const int wm = (wid >> 1) * 32, wn = (wid & 1) * 32;
    const int m0 = blockIdx.y * 64;
    const int bb = m0 >> 10;          // batch of this m-tile
    const int tb = m0 & 1023;         // t-base of this m-tile
    const int lrow = lane & 15, quad = lane >> 4;

    const int sm = tid >> 2;
    const int sk = (tid & 3) * 8;

    f32x4 acc[2][2] = {};

    for (int k0 = 0; k0 < K; k0 += 32) {
        #pragma unroll
        for (int p = 0; p < 2; p++) {
            int kk = (tid >> 4) + p * 16;          // 0..31
            int mq = tid & 15;                     // float4 index along m
            float4 v = *reinterpret_cast<const float4*>(AT + ((size_t)(bb * 512 + k0 + kk)) * 1024 + tb + mq * 4);
            As[mq * 4 + 0][kk] = bf16bits(v.x);
            As[mq * 4 + 1][kk] = bf16bits(v.y);
            As[mq * 4 + 2][kk] = bf16bits(v.z);
            As[mq * 4 + 3][kk] = bf16bits(v.w);
        }
        float4 bv = {0.f, 0.f, 0.f, 0.f};
        if (sm < N) bv = *reinterpret_cast<const float4*>(W + (size_t)sm * K + k0 + sk);
        *reinterpret_cast<float4*>(&Bs[sm][sk]) = bv;
        __syncthreads();

        frag8 a0 = *reinterpret_cast<const frag8*>(&As[wm + lrow][quad * 8]);
        frag8 a1 = *reinterpret_cast<const frag8*>(&As[wm + 16 + lrow][quad * 8]);
        frag8 b0 = *reinterpret_cast<const frag8*>(&Bs[wn + lrow][quad * 8]);
        frag8 b1 = *reinterpret_cast<const frag8*>(&Bs[wn + 16 + lrow][quad * 8]);

        acc[0][0] = __builtin_amdgcn_mfma_f32_16x16x32_bf16(a0, b0, acc[0][0], 0, 0, 0);
        acc[0][1] = __builtin_amdgcn_mfma_f32_16x16x32_bf16(a0, b1, acc[0][1], 0, 0, 0);
        acc[1][0] = __builtin_amdgcn_mfma_f32_16x16x32_bf16(a1, b0, acc[1][0], 0, 0, 0);
        acc[1][1] = __builtin_amdgcn_mfma_f32_16x16x32_bf16(a1, b1, acc[1][1], 0, 0, 0);
        __syncthreads();
    }

    #pragma unroll
    for (int mi = 0; mi < 2; mi++) {
        #pragma unroll
        for (int nj = 0; nj < 2; nj++) {
            int col = wn + nj * 16 + lrow;
            if (col >= N) continue;
            #pragma unroll
            for (int r = 0; r < 4; r++) {
                int row = m0 + wm + mi * 16 + quad * 4 + r;
                C[(size_t)row * N + col] = acc[mi][nj][r];
            }
        }
    }
}

// ---------------- full-row GEMM (N=256) with fused LN / GELU / residual / L2 ----
__global__ __launch_bounds__(256)
void rowgemm(const unsigned short* __restrict__ A,
             const unsigned short* __restrict__ W,
             const float* __restrict__ bias,
             const float* res,
             const float* g1, const float* b1, int gelu1,
             const float* g2, const float* b2,
             float* outF, unsigned short* outB, float* l2out, int K)
{
    __shared__ __align__(16) unsigned short As[16][40];
    __shared__ __align__(16) unsigned short Bs[256][40];
    __shared__ float red[4][16][2];
    __shared__ float sq[16];

    const int tid = threadIdx.x;
    const int w = tid >> 6, lane = tid & 63;
    const int lrow = lane & 15, quad = lane >> 4;
    const int m0 = blockIdx.x * 16;

    f32x4 acc[4] = {};

    for (int k0 = 0; k0 < K; k0 += 32) {
        if (tid < 64) {
            float4 av = *reinterpret_cast<const float4*>(A + (size_t)(m0 + (tid >> 2)) * K + k0 + (tid & 3) * 8);
            *reinterpret_cast<float4*>(&As[tid >> 2][(tid & 3) * 8]) = av;
        }
        #pragma unroll
        for (int i = 0; i < 4; i++) {
            int n = (tid >> 2) + i * 64;
            float4 bv = *reinterpret_cast<const float4*>(W + (size_t)n * K + k0 + (tid & 3) * 8);
            *reinterpret_cast<float4*>(&Bs[n][(tid & 3) * 8]) = bv;
        }
        __syncthreads();
        frag8 a = *reinterpret_cast<const frag8*>(&As[lrow][quad * 8]);
        #pragma unroll
        for (int nj = 0; nj < 4; nj++) {
            frag8 b = *reinterpret_cast<const frag8*>(&Bs[w * 64 + nj * 16 + lrow][quad * 8]);
            acc[nj] = __builtin_amdgcn_mfma_f32_16x16x32_bf16(a, b, acc[nj], 0, 0, 0);
        }
        __syncthreads();
    }

    float v[4][4];
    #pragma unroll
    for (int nj = 0; nj < 4; nj++) {
        int col = w * 64 + nj * 16 + lrow;
        #pragma unroll
        for (int r = 0; r < 4; r++) {
            int row = m0 + quad * 4 + r;
            float t = acc[nj][r];
            if (bias) t += bias[col];
            if (res) t += res[(size_t)row * 256 + col];
            v[nj][r] = t;
        }
    }

    if (g1) {
        #pragma unroll
        for (int r = 0; r < 4; r++) {
            float s1 = v[0][r] + v[1][r] + v[2][r] + v[3][r];
            float s2 = v[0][r]*v[0][r] + v[1][r]*v[1][r] + v[2][r]*v[2][r] + v[3][r]*v[3][r];
            s1 = row_sum16(s1); s2 = row_sum16(s2);
            if (lrow == 0) { red[w][quad * 4 + r][0] = s1; red[w][quad * 4 + r][1] = s2; }
        }
        __syncthreads();
        #pragma unroll
        for (int r = 0; r < 4; r++) {
            int rr = quad * 4 + r;
            float t1 = red[0][rr][0] + red[1][rr][0] + red[2][rr][0] + red[3][rr][0];
            float t2 = red[0][rr][1] + red[1][rr][1] + red[2][rr][1] + red[3][rr][1];
            float mu = t1 * (1.0f / 256.0f);
            float var = t2 * (1.0f / 256.0f) - mu * mu;
            float rstd = rsqrtf(var + 1e-5f);
            #pragma unroll
            for (int nj = 0; nj < 4; nj++) {
                int col = w * 64 + nj * 16 + lrow;
                float t = (v[nj][r] - mu) * rstd * g1[col] + b1[col];
                if (gelu1) t = gelu_exact(t);
                v[nj][r] = t;
            }
        }
        __syncthreads();
    } else if (gelu1) {
        #pragma unroll
        for (int nj = 0; nj < 4; nj++)
            #pragma unroll
            for (int r = 0; r < 4; r++)
                v[nj][r] = gelu_exact(v[nj][r]);
    }

    if (outF) {
        #pragma unroll
        for (int nj = 0; nj < 4; nj++) {
            int col = w * 64 + nj * 16 + lrow;
            #pragma unroll
            for (int r = 0; r < 4; r++)
                outF[(size_t)(m0 + quad * 4 + r) * 256 + col] = v[nj][r];
        }
    }

    if (l2out) {
        #pragma unroll
        for (int r = 0; r < 4; r++) {
            float s2 = v[0][r]*v[0][r] + v[1][r]*v[1][r] + v[2][r]*v[2][r] + v[3][r]*v[3][r];
            s2 = row_sum16(s2);
            if (lrow == 0) red[w][quad * 4 + r][0] = s2;
        }
        __syncthreads();
        if (tid < 16) {
            float t = red[0][tid][0] + red[1][tid][0] + red[2][tid][0] + red[3][tid][0];
            sq[tid] = sqrtf(t);
        }
        __syncthreads();
        if (tid == 0) {
            float a = 0.f;
            #pragma unroll
            for (int i = 0; i < 16; i++) a += sq[i];
            atomicAdd(l2out, a * (0.01f / 4096.0f));
        }
    }

    if (g2) {
        __syncthreads();
        #pragma unroll
        for (int r = 0; r < 4; r++) {
            float s1 = v[0][r] + v[1][r] + v[2][r] + v[3][r];
            float s2 = v[0][r]*v[0][r] + v[1][r]*v[1][r] + v[2][r]*v[2][r] + v[3][r]*v[3][r];
            s1 = row_sum16(s1); s2 = row_sum16(s2);
            if (lrow == 0) { red[w][quad * 4 + r][0] = s1; red[w][quad * 4 + r][1] = s2; }
        }
        __syncthreads();
        #pragma unroll
        for (int r = 0; r < 4; r++) {
            int rr = quad * 4 + r;
            float t1 = red[0][rr][0] + red[1][rr][0] + red[2][rr][0] + red[3][rr][0];
            float t2 = red[0][rr][1] + red[1][rr][1] + red[2][rr][1] + red[3][rr][1];
            float mu = t1 * (1.0f / 256.0f);
            float var = t2 * (1.0f / 256.0f) - mu * mu;
            float rstd = rsqrtf(var + 1e-5f);
            #pragma unroll
            for (int nj = 0; nj < 4; nj++) {
                int col = w * 64 + nj * 16 + lrow;
                outB[(size_t)(m0 + rr) * 256 + col] = bf16bits((v[nj][r] - mu) * rstd * g2[col] + b2[col]);
            }
        }
    } else if (outB) {
        #pragma unroll
        for (int nj = 0; nj < 4; nj++) {
            int col = w * 64 + nj * 16 + lrow;
            #pragma unroll
            for (int r = 0; r < 4; r++)
                outB[(size_t)(m0 + quad * 4 + r) * 256 + col] = bf16bits(v[nj][r]);
        }
    }
}

// ---------------- conv + SiLU, writing u^T [b][d][t] fp32 ----------------
// grid 512: b(4) x dtile(8,64d) x ttile(16,64t); 256 threads
__global__ __launch_bounds__(256)
void conv_silu_T(const float* __restrict__ xz, const float* __restrict__ cw,
                 const float* __restrict__ cb, float* __restrict__ ucT)
{
    __shared__ float xs[67][65];
    const int bx = blockIdx.x;
    const int b = bx >> 7;
    const int dt_ = (bx & 127) >> 4;
    const int tt = bx & 15;
    const int tid = threadIdx.x;
    const int d0 = dt_ * 64, t0 = tt * 64;

    for (int i = tid; i < 67 * 64; i += 256) {
        int rr = i >> 6, dd = i & 63;
        int tg = t0 - 3 + rr;
        xs[rr][dd] = (tg >= 0) ? xz[((size_t)(b * 1024 + tg)) * 1024 + d0 + dd] : 0.0f;
    }
    __syncthreads();

    const int tl = tid & 63, dgrp = tid >> 6;
    #pragma unroll 4
    for (int dp = 0; dp < 16; dp++) {
        int dd = dp * 4 + dgrp;
        int d = d0 + dd;
        float c0 = cw[d * 4 + 0], c1 = cw[d * 4 + 1], c2 = cw[d * 4 + 2], c3 = cw[d * 4 + 3];
        float acc = cb[d] + xs[tl][dd] * c0 + xs[tl + 1][dd] * c1 + xs[tl + 2][dd] * c2 + xs[tl + 3][dd] * c3;
        ucT[((size_t)(b * 512 + d)) * 1024 + t0 + tl] = acc * sigmoid_f(acc);
    }
}

// ---------------- dt projection + softplus, writing delta^T [b][d][t] ----------
// grid 512: b(4) x ttile(16,64t) x dgroup(8,64d); 256 threads; all operands in LDS
__global__ __launch_bounds__(256)
void dt_softplus_T(const float* __restrict__ xdbc, const float* __restrict__ dtw,
                   const float* __restrict__ dtb, float* __restrict__ dltT)
{
    __shared__ float xd[64][17];
    __shared__ float wS[64][16];
    __shared__ float bS[64];
    const int bx = blockIdx.x;
    const int b = bx >> 7;
    const int tt = (bx >> 3) & 15;
    const int dg = bx & 7;
    const int tid = threadIdx.x;
    const int t0 = tt * 64, d0 = dg * 64;

    for (int i = tid; i < 64 * 16; i += 256) {
        int t = i >> 4, k = i & 15;
        xd[t][k] = xdbc[((size_t)(b * 1024 + t0 + t)) * 48 + k];
    }
    for (int i = tid; i < 64 * 16; i += 256) {
        int dl = i >> 4, k = i & 15;
        wS[dl][k] = dtw[(d0 + dl) * 16 + k];
    }
    if (tid < 64) bS[tid] = dtb[d0 + tid];
    __syncthreads();

    const int tl = tid & 63, w = tid >> 6;
    #pragma unroll 4
    for (int di = 0; di < 16; di++) {
        int dl = w * 16 + di;
        float acc = bS[dl];
        #pragma unroll
        for (int k = 0; k < 16; k++) acc += xd[tl][k] * wS[dl][k];
        dltT[((size_t)(b * 512 + d0 + dl)) * 1024 + t0 + tl] = softplus_f(acc);
    }
}

// ---------------- B/C transpose: xdbc[.,16:48] -> BT/CT [b][s][t] ----------------
// grid 16: b(4) x ttile(4,256t); 256 threads
__global__ __launch_bounds__(256)
void bc_trans(const float* __restrict__ xdbc, float* __restrict__ BT, float* __restrict__ CT)
{
    __shared__ float sx[256][33];
    const int b = blockIdx.x >> 2;
    const int tt = blockIdx.x & 3;
    const int tid = threadIdx.x;
    const int t0 = tt * 256;

    for (int i = tid; i < 256 * 32; i += 256) {
        int t = i >> 5, c = i & 31;
        sx[t][c] = xdbc[((size_t)(b * 1024 + t0 + t)) * 48 + 16 + c];
    }
    __syncthreads();
    for (int i = tid; i < 32 * 256; i += 256) {
        int c = i >> 8, t = i & 255;
        float v = sx[t][c];
        if (c < 16) BT[((size_t)(b * 16 + c)) * 1024 + t0 + t] = v;
        else        CT[((size_t)(b * 16 + c - 16)) * 1024 + t0 + t] = v;
    }
}

// ---------------- chunked selective scan, float4 transposed loads ----------------
__global__ __launch_bounds__(1024)
void scan_chunked(const float* __restrict__ dltT, const float* __restrict__ ucT,
                  const float* __restrict__ BT, const float* __restrict__ CT,
                  const float* __restrict__ xz,
                  const float* __restrict__ A_log, const float* __restrict__ Dp,
                  unsigned short* __restrict__ y)
{
    __shared__ float aprod_s[16][64];
    __shared__ float sfin_s[16][64];
    __shared__ float sin_s[16][64];
    __shared__ float ylocal[16][64][4];
    __shared__ float ycorr[16][64][4];

    const int j = blockIdx.x;
    const int bid = (j & 7) * 64 + (j >> 3);     // XCD swizzle
    const int b = bid >> 7;
    const int d0 = (bid & 127) * 4;
    const int w = threadIdx.x >> 6;
    const int lane = threadIdx.x & 63;
    const int dsub = lane >> 4, s = lane & 15;
    const int d = d0 + dsub;

    const float Acoef = -__expf(A_log[d * 16 + s]);

    const float4* dp = reinterpret_cast<const float4*>(dltT + ((size_t)(b * 512 + d)) * 1024 + w * 64);
    const float4* up = reinterpret_cast<const float4*>(ucT  + ((size_t)(b * 512 + d)) * 1024 + w * 64);
    const float4* Bp = reinterpret_cast<const float4*>(BT + ((size_t)(b * 16 + s)) * 1024 + w * 64);
    const float4* Cp = reinterpret_cast<const float4*>(CT + ((size_t)(b * 16 + s)) * 1024 + w * 64);

    // ---- Phase A: local scan with cumprod ----
    float st = 0.0f, ap = 1.0f;
    #pragma unroll 2
    for (int q = 0; q < 16; q++) {
        float4 dt4 = dp[q], ut4 = up[q], B4 = Bp[q], C4 = Cp[q];
        const float* dtp = (const float*)&dt4;
        const float* utp = (const float*)&ut4;
        const float* Btp = (const float*)&B4;
        const float* Ctp = (const float*)&C4;
        #pragma unroll
        for (int jj = 0; jj < 4; jj++) {
            float dA = __expf(dtp[jj] * Acoef);
            st = st * dA + dtp[jj] * utp[jj] * Btp[jj];
            ap *= dA;
            float part = row_sum16(st * Ctp[jj]);
            if (s == 0) ylocal[w][q * 4 + jj][dsub] = part;
        }
    }
    aprod_s[w][lane] = ap;
    sfin_s[w][lane] = st;
    __syncthreads();

    // ---- Phase B: chunk-summary scan ----
    if (w == 0) {
        float pre = 0.0f;
        #pragma unroll
        for (int c = 0; c < 16; c++) {
            sin_s[c][lane] = pre;
            pre = sfin_s[c][lane] + aprod_s[c][lane] * pre;
        }
    }
    __syncthreads();

    // ---- Phase C: correction ----
    float g = sin_s[w][lane];
    #pragma unroll 2
    for (int q = 0; q < 16; q++) {
        float4 dt4 = dp[q], C4 = Cp[q];
        const float* dtp = (const float*)&dt4;
        const float* Ctp = (const float*)&C4;
        #pragma unroll
        for (int jj = 0; jj < 4; jj++) {
            g *= __expf(dtp[jj] * Acoef);
            float part = row_sum16(g * Ctp[jj]);
            if (s == 0) ycorr[w][q * 4 + jj][dsub] = part;
        }
    }

    // ---- vectorized epilogue: lane = t within chunk ----
    const int t = w * 64 + lane;
    const size_t row = (size_t)b * 1024 + t;
    #pragma unroll
    for (int dd = 0; dd < 4; dd++) {
        float ut = ucT[((size_t)(b * 512 + d0 + dd)) * 1024 + t];
        float zt = xz[row * 1024 + 512 + d0 + dd];
        float yv = ylocal[w][lane][dd] + ycorr[w][lane][dd] + ut * Dp[d0 + dd];
        y[row * 512 + d0 + dd] = bf16bits(yv * (zt * sigmoid_f(zt)));
    }
}

// ---------------- misc ----------------
__global__ void zero_one(float* p) { if (threadIdx.x == 0 && blockIdx.x == 0) *p = 0.0f; }

// ---------------- launcher ----------------
extern "C" void kernel_launch(void* const* d_in, const int* in_sizes, int n_in,
                              void* d_out, int out_size, void* d_ws, size_t ws_size,
                              hipStream_t stream)
{
    const float* x      = (const float*)d_in[0];
    const float* in_b   = (const float*)d_in[2];
    const float* ln_g   = (const float*)d_in[3];
    const float* ln_b   = (const float*)d_in[4];
    const float* blk_ng  = (const float*)d_in[5];
    const float* blk_nb  = (const float*)d_in[6];
    const float* blk_cw  = (const float*)d_in[8];
    const float* blk_cb  = (const float*)d_in[9];
    const float* blk_dtw = (const float*)d_in[11];
    const float* blk_dtb = (const float*)d_in[12];
    const float* blk_Alog= (const float*)d_in[13];
    const float* blk_D   = (const float*)d_in[14];
    const float* op_b   = (const float*)d_in[17];
    const float* cls_b  = (const float*)d_in[19];
    float* out = (float*)d_out;

    const int BL = 4096;
    float* ws = (float*)d_ws;
    float* h0   = ws;                         // 1,048,576
    float* xz   = h0 + 1048576;               // 4,194,304
    float* ucT  = xz + 4194304;               // 2,097,152  [b][d][t]
    float* xdbc = ucT + 2097152;              //   196,608
    float* dltT = xdbc + 196608;              // 2,097,152  [b][d][t]
    float* BT   = dltT + 2097152;             //    65,536  [b][s][t]
    float* CT   = BT + 65536;                 //    65,536  [b][s][t]
    unsigned short* wb  = (unsigned short*)(CT + 65536);
    unsigned short* hnb = wb + 1130496;       // 1,048,576
    unsigned short* ybb = hnb + 1048576;      // 2,097,152
    unsigned short* xb  = (unsigned short*)dltT;  // x bf16 (dead before dltT written)
    unsigned short* h0b = hnb;
    unsigned short* h2b = ybb;
    unsigned short* in_wb  = wb;
    unsigned short* ipw_b  = wb + 196608;
    unsigned short* xpw_b  = wb + 720896;
    unsigned short* opw_b  = wb + 770048;
    unsigned short* op_wb  = wb + 1032192;
    unsigned short* cls_wb = wb + 1097728;

    CvtArgs ca;
    ca.src[0] = x;                  ca.dst[0] = xb;     ca.n4[0] = 3145728 / 4;
    ca.src[1] = (const float*)d_in[1];  ca.dst[1] = in_wb;  ca.n4[1] = 196608 / 4;
    ca.src[2] = (const float*)d_in[7];  ca.dst[2] = ipw_b;  ca.n4[2] = 524288 / 4;
    ca.src[3] = (const float*)d_in[10]; ca.dst[3] = xpw_b;  ca.n4[3] = 49152 / 4;
    ca.src[4] = (const float*)d_in[15]; ca.dst[4] = opw_b;  ca.n4[4] = 262144 / 4;
    ca.src[5] = (const float*)d_in[16]; ca.dst[5] = op_wb;  ca.n4[5] = 65536 / 4;
    ca.src[6] = (const float*)d_in[18]; ca.dst[6] = cls_wb; ca.n4[6] = 32768 / 4;
    int total4 = (3145728 + 1130496) / 4;
    cvt_all<<<(total4 + 255) / 256, 256, 0, stream>>>(ca, total4);
    zero_one<<<1, 1, 0, stream>>>(out + (size_t)BL * 128);

    // in_proj + bias + LN + GELU -> h0 (fp32), + LN(layer0) -> hnb (bf16)
    rowgemm<<<256, 256, 0, stream>>>(xb, in_wb, in_b, nullptr,
                                     ln_g, ln_b, 1,
                                     blk_ng, blk_nb,
                                     h0, hnb, nullptr, 768);

    for (int l = 0; l < 2; l++) {
        const float* cw   = blk_cw  + (size_t)l * 512 * 4;
        const float* cb   = blk_cb  + l * 512;
        const float* dtw  = blk_dtw + (size_t)l * 512 * 16;
        const float* dtb  = blk_dtb + l * 512;
        const float* Alog = blk_Alog+ (size_t)l * 512 * 16;
        const float* Dl   = blk_D   + l * 512;
        const unsigned short* ipwl = ipw_b + (size_t)l * 262144;
        const unsigned short* xpwl = xpw_b + (size_t)l * 24576;
        const unsigned short* opwl = opw_b + (size_t)l * 131072;

        // xz = hnb @ ipw.T   (N=1024, K=256)
        gemm_mfma<<<dim3(16, 64), 256, 0, stream>>>(hnb, ipwl, nullptr, xz, 1024, 256);
        // ucT = silu(conv(u) + cb), transposed [b][d][t]
        conv_silu_T<<<512, 256, 0, stream>>>(xz, cw, cb, ucT);
        // xdbc = u @ xpw.T  (N=48, K=512), A read from ucT [b][k][t]
        gemm_at<<<dim3(1, 64), 256, 0, stream>>>(ucT, xpwl, xdbc, 48, 512);
        // BT/CT transposes + dltT (softplus(dt@dtw.T+dtb), transposed)
        bc_trans<<<16, 256, 0, stream>>>(xdbc, BT, CT);
        dt_softplus_T<<<512, 256, 0, stream>>>(xdbc, dtw, dtb, dltT);
        // scan -> ybb
        scan_chunked<<<512, 1024, 0, stream>>>(dltT, ucT, BT, CT, xz, Alog, Dl, ybb);
        // h0 += ybb @ opw.T; layer0: +LN(layer1)->hnb; layer1: ->h0b bf16 only
        if (l == 0)
            rowgemm<<<256, 256, 0, stream>>>(ybb, opwl, nullptr, h0,
                                             nullptr, nullptr, 0,
                                             blk_ng + 256, blk_nb + 256,
                                             h0, hnb, nullptr, 512);
        else
            rowgemm<<<256, 256, 0, stream>>>(ybb, opwl, nullptr, h0,
                                             nullptr, nullptr, 0,
                                             nullptr, nullptr,
                                             nullptr, h0b, nullptr, 512);
    }

    // h2 = gelu(h0b @ op_w.T + op_b) -> h2b (bf16) + fused L2 scalar
    rowgemm<<<256, 256, 0, stream>>>(h0b, op_wb, op_b, nullptr,
                                     nullptr, nullptr, 1,
                                     nullptr, nullptr,
                                     nullptr, h2b, out + (size_t)BL * 128, 256);
    // logits = h2b @ cls_w.T + cls_b -> d_out (N=128, K=256)
    gemm_mfma<<<dim3(2, 64), 256, 0, stream>>>(h2b, cls_wb, cls_b, out, 128, 256);
}

// Round 8
// 376.844 us; speedup vs baseline: 1.3981x; 1.0899x over previous
//
#include <hip/hip_runtime.h>
#include <hip/hip_bf16.h>
#include <math.h>

typedef __attribute__((ext_vector_type(8))) short frag8;   // 8 bf16 (4 VGPRs)
typedef __attribute__((ext_vector_type(4))) float f32x4;

// ---------------- device helpers ----------------
__device__ __forceinline__ float gelu_exact(float x) {
    return 0.5f * x * (1.0f + erff(x * 0.70710678118654752f));
}
__device__ __forceinline__ float softplus_f(float x) {
    return (x > 20.0f) ? x : log1pf(expf(x));
}
__device__ __forceinline__ float sigmoid_f(float x) {
    return 1.0f / (1.0f + __expf(-x));
}
__device__ __forceinline__ unsigned short bf16bits(float x) {
    __hip_bfloat16 h = __float2bfloat16(x);
    return *(unsigned short*)&h;
}
__device__ __forceinline__ float bf2f(unsigned short u) {
    unsigned int v = ((unsigned int)u) << 16;
    return __builtin_bit_cast(float, v);
}
// sum over the 16 lanes of each DPP row-of-16 — VALU-pipe only
__device__ __forceinline__ float row_sum16(float x) {
    int t;
    t = __builtin_amdgcn_update_dpp(0, __builtin_bit_cast(int, x), 0x128, 0xf, 0xf, true); // row_ror:8
    x += __builtin_bit_cast(float, t);
    t = __builtin_amdgcn_update_dpp(0, __builtin_bit_cast(int, x), 0x124, 0xf, 0xf, true); // row_ror:4
    x += __builtin_bit_cast(float, t);
    t = __builtin_amdgcn_update_dpp(0, __builtin_bit_cast(int, x), 0x122, 0xf, 0xf, true); // row_ror:2
    x += __builtin_bit_cast(float, t);
    t = __builtin_amdgcn_update_dpp(0, __builtin_bit_cast(int, x), 0x121, 0xf, 0xf, true); // row_ror:1
    x += __builtin_bit_cast(float, t);
    return x;
}
// inclusive prefix sum over the full 64-lane wave (DPP, VALU-pipe only)
__device__ __forceinline__ float prefix_sum64(float x) {
    int t;
    t = __builtin_amdgcn_update_dpp(0, __builtin_bit_cast(int, x), 0x111, 0xf, 0xf, true); // row_shr:1
    x += __builtin_bit_cast(float, t);
    t = __builtin_amdgcn_update_dpp(0, __builtin_bit_cast(int, x), 0x112, 0xf, 0xf, true); // row_shr:2
    x += __builtin_bit_cast(float, t);
    t = __builtin_amdgcn_update_dpp(0, __builtin_bit_cast(int, x), 0x114, 0xf, 0xf, true); // row_shr:4
    x += __builtin_bit_cast(float, t);
    t = __builtin_amdgcn_update_dpp(0, __builtin_bit_cast(int, x), 0x118, 0xf, 0xf, true); // row_shr:8
    x += __builtin_bit_cast(float, t);
    t = __builtin_amdgcn_update_dpp(0, __builtin_bit_cast(int, x), 0x142, 0xa, 0xf, true); // row_bcast:15 -> rows 1,3
    x += __builtin_bit_cast(float, t);
    t = __builtin_amdgcn_update_dpp(0, __builtin_bit_cast(int, x), 0x143, 0xc, 0xf, true); // row_bcast:31 -> rows 2,3
    x += __builtin_bit_cast(float, t);
    return x;
}

// ---------------- fused fp32 -> bf16 conversion ----------------
struct CvtArgs {
    const float* src[7];
    unsigned short* dst[7];
    int n4[7];
};
__global__ __launch_bounds__(256)
void cvt_all(CvtArgs a, int total4)
{
    int i = blockIdx.x * 256 + threadIdx.x;
    if (i >= total4) return;
    int seg = 0;
    while (i >= a.n4[seg]) { i -= a.n4[seg]; seg++; }
    float4 v = reinterpret_cast<const float4*>(a.src[seg])[i];
    ushort4 o;
    o.x = bf16bits(v.x); o.y = bf16bits(v.y); o.z = bf16bits(v.z); o.w = bf16bits(v.w);
    reinterpret_cast<ushort4*>(a.dst[seg])[i] = o;
}

// ---------------- setup: Acoef = -exp(A_log) for both layers + zero l2 ----------
__global__ __launch_bounds__(256)
void setup_k(const float* __restrict__ Alog, float* __restrict__ Ac, float* l2)
{
    int i = blockIdx.x * 256 + threadIdx.x;
    if (i < 16384) Ac[i] = -__expf(Alog[i]);
    if (i == 0) *l2 = 0.0f;
}

// ---------------- generic MFMA bf16 GEMM (64x64 tile) ----------------
__global__ __launch_bounds__(256)
void gemm_mfma(const unsigned short* __restrict__ A,
               const unsigned short* __restrict__ W,
               const float* __restrict__ bias,
               float* __restrict__ C,
               int N, int K)
{
    __shared__ __align__(16) unsigned short As[64][40];
    __shared__ __align__(16) unsigned short Bs[64][40];

    const int tid = threadIdx.x;
    const int wid = tid >> 6, lane = tid & 63;
    const int wm = (wid >> 1) * 32, wn = (wid & 1) * 32;
    const int m0 = blockIdx.y * 64, n0 = blockIdx.x * 64;
    const int lrow = lane & 15, quad = lane >> 4;

    const int sm = tid >> 2;
    const int sk = (tid & 3) * 8;

    f32x4 acc[2][2] = {};

    for (int k0 = 0; k0 < K; k0 += 32) {
        float4 av = *reinterpret_cast<const float4*>(A + (size_t)(m0 + sm) * K + k0 + sk);
        *reinterpret_cast<float4*>(&As[sm][sk]) = av;
        float4 bv = {0.f, 0.f, 0.f, 0.f};
        int n = n0 + sm;
        if (n < N) bv = *reinterpret_cast<const float4*>(W + (size_t)n * K + k0 + sk);
        *reinterpret_cast<float4*>(&Bs[sm][sk]) = bv;
        __syncthreads();

        frag8 a0 = *reinterpret_cast<const frag8*>(&As[wm + lrow][quad * 8]);
        frag8 a1 = *reinterpret_cast<const frag8*>(&As[wm + 16 + lrow][quad * 8]);
        frag8 b0 = *reinterpret_cast<const frag8*>(&Bs[wn + lrow][quad * 8]);
        frag8 b1 = *reinterpret_cast<const frag8*>(&Bs[wn + 16 + lrow][quad * 8]);

        acc[0][0] = __builtin_amdgcn_mfma_f32_16x16x32_bf16(a0, b0, acc[0][0], 0, 0, 0);
        acc[0][1] = __builtin_amdgcn_mfma_f32_16x16x32_bf16(a0, b1, acc[0][1], 0, 0, 0);
        acc[1][0] = __builtin_amdgcn_mfma_f32_16x16x32_bf16(a1, b0, acc[1][0], 0, 0, 0);
        acc[1][1] = __builtin_amdgcn_mfma_f32_16x16x32_bf16(a1, b1, acc[1][1], 0, 0, 0);
        __syncthreads();
    }

    #pragma unroll
    for (int mi = 0; mi < 2; mi++) {
        #pragma unroll
        for (int nj = 0; nj < 2; nj++) {
            int col = n0 + wn + nj * 16 + lrow;
            if (col >= N) continue;
            #pragma unroll
            for (int r = 0; r < 4; r++) {
                int row = m0 + wm + mi * 16 + quad * 4 + r;
                float v = acc[mi][nj][r];
                if (bias) v += bias[col];
                C[(size_t)row * N + col] = v;
            }
        }
    }
}

// ---------------- MFMA GEMM, A from ucT [B=4][K=512][T=1024] fp32 ----------------
__global__ __launch_bounds__(256)
void gemm_at(const float* __restrict__ AT,
             const unsigned short* __restrict__ W,
             float* __restrict__ C,
             int N, int K)
{
    __shared__ __align__(16) unsigned short As[64][40];
    __shared__ __align__(16) unsigned short Bs[64][40];

    const int tid = threadIdx.x;
    const int wid = tid >> 6, lane = tid & 63;
    const int wm = (wid >> 1) * 32, wn = (wid & 1) * 32;
    const int m0 = blockIdx.y * 64;
    const int bb = m0 >> 10;          // batch of this m-tile
    const int tb = m0 & 1023;         // t-base of this m-tile
    const int lrow = lane & 15, quad = lane >> 4;

    const int sm = tid >> 2;
    const int sk = (tid & 3) * 8;

    f32x4 acc[2][2] = {};

    for (int k0 = 0; k0 < K; k0 += 32) {
        #pragma unroll
        for (int p = 0; p < 2; p++) {
            int kk = (tid >> 4) + p * 16;          // 0..31
            int mq = tid & 15;                     // float4 index along m
            float4 v = *reinterpret_cast<const float4*>(AT + ((size_t)(bb * 512 + k0 + kk)) * 1024 + tb + mq * 4);
            As[mq * 4 + 0][kk] = bf16bits(v.x);
            As[mq * 4 + 1][kk] = bf16bits(v.y);
            As[mq * 4 + 2][kk] = bf16bits(v.z);
            As[mq * 4 + 3][kk] = bf16bits(v.w);
        }
        float4 bv = {0.f, 0.f, 0.f, 0.f};
        if (sm < N) bv = *reinterpret_cast<const float4*>(W + (size_t)sm * K + k0 + sk);
        *reinterpret_cast<float4*>(&Bs[sm][sk]) = bv;
        __syncthreads();

        frag8 a0 = *reinterpret_cast<const frag8*>(&As[wm + lrow][quad * 8]);
        frag8 a1 = *reinterpret_cast<const frag8*>(&As[wm + 16 + lrow][quad * 8]);
        frag8 b0 = *reinterpret_cast<const frag8*>(&Bs[wn + lrow][quad * 8]);
        frag8 b1 = *reinterpret_cast<const frag8*>(&Bs[wn + 16 + lrow][quad * 8]);

        acc[0][0] = __builtin_amdgcn_mfma_f32_16x16x32_bf16(a0, b0, acc[0][0], 0, 0, 0);
        acc[0][1] = __builtin_amdgcn_mfma_f32_16x16x32_bf16(a0, b1, acc[0][1], 0, 0, 0);
        acc[1][0] = __builtin_amdgcn_mfma_f32_16x16x32_bf16(a1, b0, acc[1][0], 0, 0, 0);
        acc[1][1] = __builtin_amdgcn_mfma_f32_16x16x32_bf16(a1, b1, acc[1][1], 0, 0, 0);
        __syncthreads();
    }

    #pragma unroll
    for (int mi = 0; mi < 2; mi++) {
        #pragma unroll
        for (int nj = 0; nj < 2; nj++) {
            int col = wn + nj * 16 + lrow;
            if (col >= N) continue;
            #pragma unroll
            for (int r = 0; r < 4; r++) {
                int row = m0 + wm + mi * 16 + quad * 4 + r;
                C[(size_t)row * N + col] = acc[mi][nj][r];
            }
        }
    }
}

// ---------------- full-row GEMM (N=256) with fused LN / GELU / residual / L2 ----
__global__ __launch_bounds__(256)
void rowgemm(const unsigned short* __restrict__ A,
             const unsigned short* __restrict__ W,
             const float* __restrict__ bias,
             const float* res,
             const float* g1, const float* b1, int gelu1,
             const float* g2, const float* b2,
             float* outF, unsigned short* outB, float* l2out, int K)
{
    __shared__ __align__(16) unsigned short As[16][40];
    __shared__ __align__(16) unsigned short Bs[256][40];
    __shared__ float red[4][16][2];
    __shared__ float sq[16];

    const int tid = threadIdx.x;
    const int w = tid >> 6, lane = tid & 63;
    const int lrow = lane & 15, quad = lane >> 4;
    const int m0 = blockIdx.x * 16;

    f32x4 acc[4] = {};

    for (int k0 = 0; k0 < K; k0 += 32) {
        if (tid < 64) {
            float4 av = *reinterpret_cast<const float4*>(A + (size_t)(m0 + (tid >> 2)) * K + k0 + (tid & 3) * 8);
            *reinterpret_cast<float4*>(&As[tid >> 2][(tid & 3) * 8]) = av;
        }
        #pragma unroll
        for (int i = 0; i < 4; i++) {
            int n = (tid >> 2) + i * 64;
            float4 bv = *reinterpret_cast<const float4*>(W + (size_t)n * K + k0 + (tid & 3) * 8);
            *reinterpret_cast<float4*>(&Bs[n][(tid & 3) * 8]) = bv;
        }
        __syncthreads();
        frag8 a = *reinterpret_cast<const frag8*>(&As[lrow][quad * 8]);
        #pragma unroll
        for (int nj = 0; nj < 4; nj++) {
            frag8 b = *reinterpret_cast<const frag8*>(&Bs[w * 64 + nj * 16 + lrow][quad * 8]);
            acc[nj] = __builtin_amdgcn_mfma_f32_16x16x32_bf16(a, b, acc[nj], 0, 0, 0);
        }
        __syncthreads();
    }

    float v[4][4];
    #pragma unroll
    for (int nj = 0; nj < 4; nj++) {
        int col = w * 64 + nj * 16 + lrow;
        #pragma unroll
        for (int r = 0; r < 4; r++) {
            int row = m0 + quad * 4 + r;
            float t = acc[nj][r];
            if (bias) t += bias[col];
            if (res) t += res[(size_t)row * 256 + col];
            v[nj][r] = t;
        }
    }

    if (g1) {
        #pragma unroll
        for (int r = 0; r < 4; r++) {
            float s1 = v[0][r] + v[1][r] + v[2][r] + v[3][r];
            float s2 = v[0][r]*v[0][r] + v[1][r]*v[1][r] + v[2][r]*v[2][r] + v[3][r]*v[3][r];
            s1 = row_sum16(s1); s2 = row_sum16(s2);
            if (lrow == 0) { red[w][quad * 4 + r][0] = s1; red[w][quad * 4 + r][1] = s2; }
        }
        __syncthreads();
        #pragma unroll
        for (int r = 0; r < 4; r++) {
            int rr = quad * 4 + r;
            float t1 = red[0][rr][0] + red[1][rr][0] + red[2][rr][0] + red[3][rr][0];
            float t2 = red[0][rr][1] + red[1][rr][1] + red[2][rr][1] + red[3][rr][1];
            float mu = t1 * (1.0f / 256.0f);
            float var = t2 * (1.0f / 256.0f) - mu * mu;
            float rstd = rsqrtf(var + 1e-5f);
            #pragma unroll
            for (int nj = 0; nj < 4; nj++) {
                int col = w * 64 + nj * 16 + lrow;
                float t = (v[nj][r] - mu) * rstd * g1[col] + b1[col];
                if (gelu1) t = gelu_exact(t);
                v[nj][r] = t;
            }
        }
        __syncthreads();
    } else if (gelu1) {
        #pragma unroll
        for (int nj = 0; nj < 4; nj++)
            #pragma unroll
            for (int r = 0; r < 4; r++)
                v[nj][r] = gelu_exact(v[nj][r]);
    }

    if (outF) {
        #pragma unroll
        for (int nj = 0; nj < 4; nj++) {
            int col = w * 64 + nj * 16 + lrow;
            #pragma unroll
            for (int r = 0; r < 4; r++)
                outF[(size_t)(m0 + quad * 4 + r) * 256 + col] = v[nj][r];
        }
    }

    if (l2out) {
        #pragma unroll
        for (int r = 0; r < 4; r++) {
            float s2 = v[0][r]*v[0][r] + v[1][r]*v[1][r] + v[2][r]*v[2][r] + v[3][r]*v[3][r];
            s2 = row_sum16(s2);
            if (lrow == 0) red[w][quad * 4 + r][0] = s2;
        }
        __syncthreads();
        if (tid < 16) {
            float t = red[0][tid][0] + red[1][tid][0] + red[2][tid][0] + red[3][tid][0];
            sq[tid] = sqrtf(t);
        }
        __syncthreads();
        if (tid == 0) {
            float a = 0.f;
            #pragma unroll
            for (int i = 0; i < 16; i++) a += sq[i];
            atomicAdd(l2out, a * (0.01f / 4096.0f));
        }
    }

    if (g2) {
        __syncthreads();
        #pragma unroll
        for (int r = 0; r < 4; r++) {
            float s1 = v[0][r] + v[1][r] + v[2][r] + v[3][r];
            float s2 = v[0][r]*v[0][r] + v[1][r]*v[1][r] + v[2][r]*v[2][r] + v[3][r]*v[3][r];
            s1 = row_sum16(s1); s2 = row_sum16(s2);
            if (lrow == 0) { red[w][quad * 4 + r][0] = s1; red[w][quad * 4 + r][1] = s2; }
        }
        __syncthreads();
        #pragma unroll
        for (int r = 0; r < 4; r++) {
            int rr = quad * 4 + r;
            float t1 = red[0][rr][0] + red[1][rr][0] + red[2][rr][0] + red[3][rr][0];
            float t2 = red[0][rr][1] + red[1][rr][1] + red[2][rr][1] + red[3][rr][1];
            float mu = t1 * (1.0f / 256.0f);
            float var = t2 * (1.0f / 256.0f) - mu * mu;
            float rstd = rsqrtf(var + 1e-5f);
            #pragma unroll
            for (int nj = 0; nj < 4; nj++) {
                int col = w * 64 + nj * 16 + lrow;
                outB[(size_t)(m0 + rr) * 256 + col] = bf16bits((v[nj][r] - mu) * rstd * g2[col] + b2[col]);
            }
        }
    } else if (outB) {
        #pragma unroll
        for (int nj = 0; nj < 4; nj++) {
            int col = w * 64 + nj * 16 + lrow;
            #pragma unroll
            for (int r = 0; r < 4; r++)
                outB[(size_t)(m0 + quad * 4 + r) * 256 + col] = bf16bits(v[nj][r]);
        }
    }
}

// ---------------- conv + SiLU -> ucT [b][d][t] fp32 ; silu(z) -> szT bf16 -------
// grid 1024: b(4) x dtile(16) x ttile(16); dtile<8: conv path (u), else z path
__global__ __launch_bounds__(256)
void conv_silu_T(const float* __restrict__ xz, const float* __restrict__ cw,
                 const float* __restrict__ cb, float* __restrict__ ucT,
                 unsigned short* __restrict__ szT)
{
    __shared__ float xs[67][65];
    const int bx = blockIdx.x;
    const int b = bx >> 8;
    const int dt_ = (bx & 255) >> 4;
    const int tt = bx & 15;
    const int tid = threadIdx.x;
    const int t0 = tt * 64;
    const int tl = tid & 63, dgrp = tid >> 6;

    if (dt_ < 8) {
        const int d0 = dt_ * 64;
        for (int i = tid; i < 67 * 64; i += 256) {
            int rr = i >> 6, dd = i & 63;
            int tg = t0 - 3 + rr;
            xs[rr][dd] = (tg >= 0) ? xz[((size_t)(b * 1024 + tg)) * 1024 + d0 + dd] : 0.0f;
        }
        __syncthreads();
        #pragma unroll 4
        for (int dp = 0; dp < 16; dp++) {
            int dd = dp * 4 + dgrp;
            int d = d0 + dd;
            float c0 = cw[d * 4 + 0], c1 = cw[d * 4 + 1], c2 = cw[d * 4 + 2], c3 = cw[d * 4 + 3];
            float acc = cb[d] + xs[tl][dd] * c0 + xs[tl + 1][dd] * c1 + xs[tl + 2][dd] * c2 + xs[tl + 3][dd] * c3;
            ucT[((size_t)(b * 512 + d)) * 1024 + t0 + tl] = acc * sigmoid_f(acc);
        }
    } else {
        const int z0 = (dt_ - 8) * 64;     // z channel base (within 512)
        for (int i = tid; i < 64 * 64; i += 256) {
            int rr = i >> 6, dd = i & 63;
            xs[rr][dd] = xz[((size_t)(b * 1024 + t0 + rr)) * 1024 + 512 + z0 + dd];
        }
        __syncthreads();
        #pragma unroll 4
        for (int dp = 0; dp < 16; dp++) {
            int dd = dp * 4 + dgrp;
            float v = xs[tl][dd];
            szT[((size_t)(b * 512 + z0 + dd)) * 1024 + t0 + tl] = bf16bits(v * sigmoid_f(v));
        }
    }
}

// ---------------- dt proj + softplus -> dltT ; fused B/C transpose --------------
// grid 512: b(4) x ttile(16,64t) x dgroup(8,64d); 256 threads
__global__ __launch_bounds__(256)
void dtbc(const float* __restrict__ xdbc, const float* __restrict__ dtw,
          const float* __restrict__ dtb, float* __restrict__ dltT,
          float* __restrict__ BT, float* __restrict__ CT)
{
    __shared__ float xd[64][17];
    __shared__ float wS[64][16];
    __shared__ float bS[64];
    const int bx = blockIdx.x;
    const int b = bx >> 7;
    const int tt = (bx >> 3) & 15;
    const int dg = bx & 7;
    const int tid = threadIdx.x;
    const int t0 = tt * 64, d0 = dg * 64;

    for (int i = tid; i < 64 * 16; i += 256) {
        int t = i >> 4, k = i & 15;
        xd[t][k] = xdbc[((size_t)(b * 1024 + t0 + t)) * 48 + k];
    }
    for (int i = tid; i < 64 * 16; i += 256) {
        int dl = i >> 4, k = i & 15;
        wS[dl][k] = dtw[(d0 + dl) * 16 + k];
    }
    if (tid < 64) bS[tid] = dtb[d0 + tid];
    __syncthreads();

    const int tl = tid & 63, w = tid >> 6;
    #pragma unroll 4
    for (int di = 0; di < 16; di++) {
        int dl = w * 16 + di;
        float acc = bS[dl];
        #pragma unroll
        for (int k = 0; k < 16; k++) acc += xd[tl][k] * wS[dl][k];
        dltT[((size_t)(b * 512 + d0 + dl)) * 1024 + t0 + tl] = softplus_f(acc);
    }

    // fused B/C transpose: this block handles columns [dg*4, dg*4+4) of the 32
    {
        int c = tid >> 6;            // 0..3
        int t = tid & 63;
        int col = dg * 4 + c;        // 0..31
        float v = xdbc[((size_t)(b * 1024 + t0 + t)) * 48 + 16 + col];
        if (col < 16) BT[((size_t)(b * 16 + col)) * 1024 + t0 + t] = v;
        else          CT[((size_t)(b * 16 + col - 16)) * 1024 + t0 + t] = v;
    }
}

// ---------------- chunked selective scan ----------------------------------------
// Phase A: serial local scan (lane = (dsub,s)). Phase B: chunk combine (wave 0).
// Phase C: lane = t; prefix-sum of dt -> closed-form correction + fused epilogue.
__global__ __launch_bounds__(1024)
void scan_chunked(const float* __restrict__ dltT, const float* __restrict__ ucT,
                  const float* __restrict__ BT, const float* __restrict__ CT,
                  const unsigned short* __restrict__ szT,
                  const float* __restrict__ Ac,       // per-layer [512*16] = -exp(A_log)
                  const float* __restrict__ Dp,
                  unsigned short* __restrict__ y)
{
    __shared__ float aprod_s[16][64];
    __shared__ float sfin_s[16][64];
    __shared__ float sin_s[16][64];
    __shared__ __align__(16) float ylocal[16][64][4];

    const int j = blockIdx.x;
    const int bid = (j & 7) * 64 + (j >> 3);     // XCD swizzle
    const int b = bid >> 7;
    const int d0 = (bid & 127) * 4;
    const int w = threadIdx.x >> 6;
    const int lane = threadIdx.x & 63;
    const int dsub = lane >> 4, s = lane & 15;
    const int d = d0 + dsub;

    const float Acoef = Ac[d * 16 + s];

    const float4* dp = reinterpret_cast<const float4*>(dltT + ((size_t)(b * 512 + d)) * 1024 + w * 64);
    const float4* up = reinterpret_cast<const float4*>(ucT  + ((size_t)(b * 512 + d)) * 1024 + w * 64);
    const float4* Bp = reinterpret_cast<const float4*>(BT + ((size_t)(b * 16 + s)) * 1024 + w * 64);
    const float4* Cp = reinterpret_cast<const float4*>(CT + ((size_t)(b * 16 + s)) * 1024 + w * 64);

    // ---- Phase A: local scan with cumprod ----
    float st = 0.0f, ap = 1.0f;
    #pragma unroll 2
    for (int q = 0; q < 16; q++) {
        float4 dt4 = dp[q], ut4 = up[q], B4 = Bp[q], C4 = Cp[q];
        const float* dtp = (const float*)&dt4;
        const float* utp = (const float*)&ut4;
        const float* Btp = (const float*)&B4;
        const float* Ctp = (const float*)&C4;
        #pragma unroll
        for (int jj = 0; jj < 4; jj++) {
            float dA = __expf(dtp[jj] * Acoef);
            st = st * dA + dtp[jj] * utp[jj] * Btp[jj];
            ap *= dA;
            float part = row_sum16(st * Ctp[jj]);
            if (s == 0) ylocal[w][q * 4 + jj][dsub] = part;
        }
    }
    aprod_s[w][lane] = ap;
    sfin_s[w][lane] = st;
    __syncthreads();

    // ---- Phase B: chunk-summary scan (wave 0) ----
    if (w == 0) {
        float pre = 0.0f;
        #pragma unroll
        for (int c = 0; c < 16; c++) {
            sin_s[c][lane] = pre;
            pre = sfin_s[c][lane] + aprod_s[c][lane] * pre;
        }
    }
    __syncthreads();

    // ---- Phase C: lane = t; correction via prefix sums + epilogue ----
    const int t = w * 64 + lane;
    float cums[4];
    #pragma unroll
    for (int dd = 0; dd < 4; dd++)
        cums[dd] = dltT[((size_t)(b * 512 + d0 + dd)) * 1024 + t];
    #pragma unroll
    for (int dd = 0; dd < 4; dd++)
        cums[dd] = prefix_sum64(cums[dd]);

    float4 yl = *reinterpret_cast<const float4*>(&ylocal[w][lane][0]);
    float acc[4] = { yl.x, yl.y, yl.z, yl.w };

    #pragma unroll
    for (int sq = 0; sq < 4; sq++) {
        float Cs[4];
        #pragma unroll
        for (int jj = 0; jj < 4; jj++)
            Cs[jj] = CT[((size_t)(b * 16 + sq * 4 + jj)) * 1024 + t];
        #pragma unroll
        for (int dd = 0; dd < 4; dd++) {
            float4 sin4 = *reinterpret_cast<const float4*>(&sin_s[w][dd * 16 + sq * 4]);
            const float* sp = (const float*)&sin4;
            #pragma unroll
            for (int jj = 0; jj < 4; jj++) {
                float ac = Ac[(d0 + dd) * 16 + sq * 4 + jj];   // uniform -> scalar load
                acc[dd] += sp[jj] * Cs[jj] * __expf(ac * cums[dd]);
            }
        }
    }

    const size_t row = (size_t)b * 1024 + t;
    #pragma unroll
    for (int dd = 0; dd < 4; dd++) {
        float ut = ucT[((size_t)(b * 512 + d0 + dd)) * 1024 + t];
        float sz = bf2f(szT[((size_t)(b * 512 + d0 + dd)) * 1024 + t]);
        float yv = acc[dd] + ut * Dp[d0 + dd];
        y[row * 512 + d0 + dd] = bf16bits(yv * sz);
    }
}

// ---------------- launcher ----------------
extern "C" void kernel_launch(void* const* d_in, const int* in_sizes, int n_in,
                              void* d_out, int out_size, void* d_ws, size_t ws_size,
                              hipStream_t stream)
{
    const float* x      = (const float*)d_in[0];
    const float* in_b   = (const float*)d_in[2];
    const float* ln_g   = (const float*)d_in[3];
    const float* ln_b   = (const float*)d_in[4];
    const float* blk_ng  = (const float*)d_in[5];
    const float* blk_nb  = (const float*)d_in[6];
    const float* blk_cw  = (const float*)d_in[8];
    const float* blk_cb  = (const float*)d_in[9];
    const float* blk_dtw = (const float*)d_in[11];
    const float* blk_dtb = (const float*)d_in[12];
    const float* blk_Alog= (const float*)d_in[13];
    const float* blk_D   = (const float*)d_in[14];
    const float* op_b   = (const float*)d_in[17];
    const float* cls_b  = (const float*)d_in[19];
    float* out = (float*)d_out;

    const int BL = 4096;
    float* ws = (float*)d_ws;
    float* h0   = ws;                         // 1,048,576
    float* xz   = h0 + 1048576;               // 4,194,304
    float* ucT  = xz + 4194304;               // 2,097,152  [b][d][t]
    float* xdbc = ucT + 2097152;              //   196,608
    float* dltT = xdbc + 196608;              // 2,097,152  [b][d][t]
    float* BT   = dltT + 2097152;             //    65,536  [b][s][t]
    float* CT   = BT + 65536;                 //    65,536  [b][s][t]
    float* Ac   = CT + 65536;                 //    16,384  (2 layers of 512x16)
    unsigned short* szT = (unsigned short*)(Ac + 16384);  // 2,097,152  [b][d][t] bf16
    unsigned short* wb  = szT + 2097152;      // 1,130,496
    unsigned short* hnb = wb + 1130496;       // 1,048,576
    unsigned short* ybb = hnb + 1048576;      // 2,097,152
    unsigned short* xb  = (unsigned short*)dltT;  // x bf16 (dead before dltT written)
    unsigned short* h0b = hnb;
    unsigned short* h2b = ybb;
    unsigned short* in_wb  = wb;
    unsigned short* ipw_b  = wb + 196608;
    unsigned short* xpw_b  = wb + 720896;
    unsigned short* opw_b  = wb + 770048;
    unsigned short* op_wb  = wb + 1032192;
    unsigned short* cls_wb = wb + 1097728;

    CvtArgs ca;
    ca.src[0] = x;                  ca.dst[0] = xb;     ca.n4[0] = 3145728 / 4;
    ca.src[1] = (const float*)d_in[1];  ca.dst[1] = in_wb;  ca.n4[1] = 196608 / 4;
    ca.src[2] = (const float*)d_in[7];  ca.dst[2] = ipw_b;  ca.n4[2] = 524288 / 4;
    ca.src[3] = (const float*)d_in[10]; ca.dst[3] = xpw_b;  ca.n4[3] = 49152 / 4;
    ca.src[4] = (const float*)d_in[15]; ca.dst[4] = opw_b;  ca.n4[4] = 262144 / 4;
    ca.src[5] = (const float*)d_in[16]; ca.dst[5] = op_wb;  ca.n4[5] = 65536 / 4;
    ca.src[6] = (const float*)d_in[18]; ca.dst[6] = cls_wb; ca.n4[6] = 32768 / 4;
    int total4 = (3145728 + 1130496) / 4;
    cvt_all<<<(total4 + 255) / 256, 256, 0, stream>>>(ca, total4);
    setup_k<<<64, 256, 0, stream>>>(blk_Alog, Ac, out + (size_t)BL * 128);

    // in_proj + bias + LN + GELU -> h0 (fp32), + LN(layer0) -> hnb (bf16)
    rowgemm<<<256, 256, 0, stream>>>(xb, in_wb, in_b, nullptr,
                                     ln_g, ln_b, 1,
                                     blk_ng, blk_nb,
                                     h0, hnb, nullptr, 768);

    for (int l = 0; l < 2; l++) {
        const float* cw   = blk_cw  + (size_t)l * 512 * 4;
        const float* cb   = blk_cb  + l * 512;
        const float* dtw  = blk_dtw + (size_t)l * 512 * 16;
        const float* dtb  = blk_dtb + l * 512;
        const float* Dl   = blk_D   + l * 512;
        const unsigned short* ipwl = ipw_b + (size_t)l * 262144;
        const unsigned short* xpwl = xpw_b + (size_t)l * 24576;
        const unsigned short* opwl = opw_b + (size_t)l * 131072;

        // xz = hnb @ ipw.T   (N=1024, K=256)
        gemm_mfma<<<dim3(16, 64), 256, 0, stream>>>(hnb, ipwl, nullptr, xz, 1024, 256);
        // ucT = silu(conv(u)+cb) [b][d][t]; szT = bf16(silu(z)) [b][d][t]
        conv_silu_T<<<1024, 256, 0, stream>>>(xz, cw, cb, ucT, szT);
        // xdbc = u @ xpw.T  (N=48, K=512), A read from ucT [b][k][t]
        gemm_at<<<dim3(1, 64), 256, 0, stream>>>(ucT, xpwl, xdbc, 48, 512);
        // dltT (softplus) + fused BT/CT transpose
        dtbc<<<512, 256, 0, stream>>>(xdbc, dtw, dtb, dltT, BT, CT);
        // scan -> ybb
        scan_chunked<<<512, 1024, 0, stream>>>(dltT, ucT, BT, CT, szT,
                                               Ac + (size_t)l * 8192, Dl, ybb);
        // h0 += ybb @ opw.T; layer0: +LN(layer1)->hnb; layer1: ->h0b bf16 only
        if (l == 0)
            rowgemm<<<256, 256, 0, stream>>>(ybb, opwl, nullptr, h0,
                                             nullptr, nullptr, 0,
                                             blk_ng + 256, blk_nb + 256,
                                             h0, hnb, nullptr, 512);
        else
            rowgemm<<<256, 256, 0, stream>>>(ybb, opwl, nullptr, h0,
                                             nullptr, nullptr, 0,
                                             nullptr, nullptr,
                                             nullptr, h0b, nullptr, 512);
    }

    // h2 = gelu(h0b @ op_w.T + op_b) -> h2b (bf16) + fused L2 scalar
    rowgemm<<<256, 256, 0, stream>>>(h0b, op_wb, op_b, nullptr,
                                     nullptr, nullptr, 1,
                                     nullptr, nullptr,
                                     nullptr, h2b, out + (size_t)BL * 128, 256);
    // logits = h2b @ cls_w.T + cls_b -> d_out (N=128, K=256)
    gemm_mfma<<<dim3(2, 64), 256, 0, stream>>>(h2b, cls_wb, cls_b, out, 128, 256);
}